// Round 6
// baseline (1895.766 us; speedup 1.0000x reference)
//
#include <hip/hip_runtime.h>
#include <hip/hip_cooperative_groups.h>

namespace cg = cooperative_groups;

#define DD 4096
#define HH 8192

enum Stage { S_X0 = 0, S_TANH, S_BIASOUT, S_PMUL, S_COPY, S_S2 };

struct Params {
    const float *h, *c, *W1, *b1, *W2, *b2;
    float *out;
    float *P1, *P2, *P3, *P4, *P5, *P6;
    float *s0, *t0, *a1, *C2;
};

// One split-K GEMV phase inside the persistent kernel.
// prologue: build x[k0:k0+KS) in LDS (from h/c or by reducing Pprev + elementwise)
// stream:   Pout[by][ncol..ncol+3] = sum_k x[k] * W[k][ncol..]
template <int STAGE, int KS, int SPREV, int KPREV, int NTOT, int BX>
__device__ inline void phase(int b, const float* __restrict__ W,
                             const float* __restrict__ Pprev, float* __restrict__ Pout,
                             const Params& p, float* xs, float* part)
{
    const int tid = threadIdx.x;
    const int bx = b % BX;
    const int by = b / BX;
    const int k0 = by * KS;
    constexpr int GROUPS = 256 / KS;

    if constexpr (STAGE == S_X0) {
        if (tid < KS) {
            int k = k0 + tid;
            xs[tid] = (k < DD) ? p.h[k] : p.c[k - DD];
        }
    } else {
        const int g = tid / KS, j = tid % KS;
        float acc = 0.f;
        for (int s = g; s < SPREV; s += GROUPS)
            acc += Pprev[(size_t)s * KPREV + k0 + j];
        part[g * KS + j] = acc;
        __syncthreads();
        if (tid < KS) {
            const int k = k0 + tid;
            float tot = 0.f;
#pragma unroll
            for (int g2 = 0; g2 < GROUPS; ++g2) tot += part[g2 * KS + tid];
            float xv;
            if constexpr (STAGE == S_TANH) {
                float s = tanhf(tot + p.b1[k]);
                xv = s;
                if (bx == 0) { p.s0[k] = s; p.t0[k] = 1.f - s * s; }
            } else if constexpr (STAGE == S_BIASOUT) {
                xv = tot + p.b2[k];
                if (bx == 0) p.out[k] = xv;
            } else if constexpr (STAGE == S_PMUL) {
                xv = p.t0[k] * tot;
                if (bx == 0) p.a1[k] = tot;
            } else if constexpr (STAGE == S_COPY) {
                xv = tot;
            } else { // S_S2
                float a1v = p.a1[k];
                xv = p.t0[k] * (tot - p.s0[k] * a1v * a1v);
            }
            xs[tid] = xv;
        }
    }
    __syncthreads();

    const int ncol = bx * 1024 + tid * 4;
    const float* Wp = W + (size_t)k0 * NTOT + ncol;
    float ax = 0.f, ay = 0.f, az = 0.f, aw = 0.f;
#pragma unroll 4
    for (int k = 0; k < KS; ++k) {
        const float xv = xs[k];
        const float4 w = *reinterpret_cast<const float4*>(Wp + (size_t)k * NTOT);
        ax = fmaf(xv, w.x, ax);
        ay = fmaf(xv, w.y, ay);
        az = fmaf(xv, w.z, az);
        aw = fmaf(xv, w.w, aw);
    }
    *reinterpret_cast<float4*>(Pout + (size_t)by * NTOT + ncol) =
        make_float4(ax, ay, az, aw);
}

__global__ void __launch_bounds__(256, 4) taylor_fused(Params p) {
    cg::grid_group grid = cg::this_grid();
    __shared__ float xs[64];
    __shared__ float part[256];
    const int b = blockIdx.x;
    const int tid = threadIdx.x;

    // P1: a0 partials = concat(h,c) @ W1   (K=8192, N=8192), 8x128 tiles
    phase<S_X0, 64, 1, 1, HH, 8>(b, p.W1, nullptr, p.P1, p, xs, part);
    __threadfence(); grid.sync();
    // P2: s0=tanh(a0+b1); Fr = s0 @ W2     (K=8192, N=4096), 4x256
    phase<S_TANH, 32, 128, HH, DD, 4>(b, p.W2, p.P1, p.P2, p, xs, part);
    __threadfence(); grid.sync();
    // P3: Ff=Fr+b2 -> out; a1 = Ff @ W1top (K=4096, N=8192), 8x128
    phase<S_BIASOUT, 32, 256, DD, HH, 8>(b, p.W1, p.P2, p.P3, p, xs, part);
    __threadfence(); grid.sync();
    // P4: p1=t0*a1; v = p1 @ W2            (K=8192, N=4096), 4x256
    phase<S_PMUL, 32, 128, HH, DD, 4>(b, p.W2, p.P3, p.P4, p, xs, part);
    __threadfence(); grid.sync();
    // P5: a2 = v @ W1top                   (K=4096, N=8192), 8x128
    phase<S_COPY, 32, 256, DD, HH, 8>(b, p.W1, p.P4, p.P5, p, xs, part);
    __threadfence(); grid.sync();
    // P6: s2=t0*(a2-s0*a1^2); C2p = s2@W2  (K=8192, N=4096), 4x256
    phase<S_S2, 32, 128, HH, DD, 4>(b, p.W2, p.P5, p.P6, p, xs, part);
    __threadfence(); grid.sync();

    // C2[n] = sum_s P6[s][n]
    if (b < 16) {
        const int n = b * 256 + tid;
        float acc = 0.f;
#pragma unroll 8
        for (int s = 0; s < 256; ++s) acc += p.P6[(size_t)s * DD + n];
        p.C2[n] = acc;
    }
    __threadfence(); grid.sync();

    // out[DD] = mean(C2^2)
    if (b == 0) {
        float s = 0.f;
        for (int i = tid; i < DD; i += 256) {
            float v = p.C2[i];
            s = fmaf(v, v, s);
        }
        for (int off = 32; off; off >>= 1) s += __shfl_down(s, off);
        if ((tid & 63) == 0) part[tid >> 6] = s;
        __syncthreads();
        if (tid == 0) p.out[DD] = (part[0] + part[1] + part[2] + part[3]) / (float)DD;
    }
}

extern "C" void kernel_launch(void* const* d_in, const int* in_sizes, int n_in,
                              void* d_out, int out_size, void* d_ws, size_t ws_size,
                              hipStream_t stream) {
    float* ws = (float*)d_ws;

    Params p;
    p.h  = (const float*)d_in[0];
    p.c  = (const float*)d_in[3];
    p.W1 = (const float*)d_in[4];   // (DD+CC) x HH row-major
    p.b1 = (const float*)d_in[5];
    p.W2 = (const float*)d_in[6];   // HH x DD row-major
    p.b2 = (const float*)d_in[7];
    p.out = (float*)d_out;          // [0..4095]=dydt, [4096]=mean(drdt^2)

    p.P1 = ws;                      // 128 x 8192
    p.P2 = p.P1 + 1048576;          // 256 x 4096
    p.P3 = p.P2 + 1048576;          // 128 x 8192
    p.P4 = p.P3 + 1048576;          // 256 x 4096
    p.P5 = p.P4 + 1048576;          // 128 x 8192
    p.P6 = p.P5 + 1048576;          // 256 x 4096
    p.s0 = p.P6 + 1048576;          // 8192
    p.t0 = p.s0 + 8192;             // 8192
    p.a1 = p.t0 + 8192;             // 8192
    p.C2 = p.a1 + 8192;             // 4096

    void* args[] = { &p };
    hipLaunchCooperativeKernel((void*)taylor_fused, dim3(1024), dim3(256),
                               args, 0, stream);
}

// Round 7
// 226.242 us; speedup vs baseline: 8.3794x; 8.3794x over previous
//
#include <hip/hip_runtime.h>

#define DD 4096
#define HH 8192

enum Stage { S_X0 = 0, S_TANH, S_BIASOUT, S_PMUL, S_COPY, S_S2 };

// ---------------- split-K GEMV phase ----------------
// prologue: build x[k0:k0+KS) in LDS (from h/c, or reduce Pprev splits + elementwise)
// stream:   each thread 8 cols (two float4 at ncol and ncol+1024), 32B/lane/row
// Pout[by][n] = sum_{k in slice by} x[k] * W[k][n]
template <int STAGE, int KS, int SPREV, int KPREV, int NTOT, int BX>
__global__ __launch_bounds__(256) void gemv_phase(
    const float* __restrict__ W, const float* __restrict__ Pprev,
    float* __restrict__ Pout,
    const float* __restrict__ h, const float* __restrict__ c,
    const float* __restrict__ b1, const float* __restrict__ b2,
    float* __restrict__ s0g, float* __restrict__ t0g, float* __restrict__ a1g,
    float* __restrict__ outv)
{
    constexpr int GROUPS = 256 / KS;
    __shared__ float xs[KS];
    __shared__ float part[GROUPS * KS];
    const int tid = threadIdx.x;
    const int bx = blockIdx.x;
    const int by = blockIdx.y;
    const int k0 = by * KS;

    if constexpr (STAGE == S_X0) {
        if (tid < KS) {
            int k = k0 + tid;
            xs[tid] = (k < DD) ? h[k] : c[k - DD];
        }
    } else {
        const int g = tid / KS, j = tid % KS;
        float acc = 0.f;
        for (int s = g; s < SPREV; s += GROUPS)
            acc += Pprev[(size_t)s * KPREV + k0 + j];
        part[g * KS + j] = acc;
        __syncthreads();
        if (tid < KS) {
            const int k = k0 + tid;
            float tot = 0.f;
#pragma unroll
            for (int g2 = 0; g2 < GROUPS; ++g2) tot += part[g2 * KS + tid];
            float xv;
            if constexpr (STAGE == S_TANH) {
                float s = tanhf(tot + b1[k]);
                xv = s;
                if (bx == 0) { s0g[k] = s; t0g[k] = 1.f - s * s; }
            } else if constexpr (STAGE == S_BIASOUT) {
                xv = tot + b2[k];
                if (bx == 0) outv[k] = xv;
            } else if constexpr (STAGE == S_PMUL) {
                xv = t0g[k] * tot;
                if (bx == 0) a1g[k] = tot;
            } else if constexpr (STAGE == S_COPY) {
                xv = tot;
            } else { // S_S2
                float a1v = a1g[k];
                xv = t0g[k] * (tot - s0g[k] * a1v * a1v);
            }
            xs[tid] = xv;
        }
    }
    __syncthreads();

    const int ncol = bx * 2048 + tid * 4;
    const float* Wp = W + (size_t)k0 * NTOT + ncol;
    float a0 = 0.f, a1 = 0.f, a2 = 0.f, a3 = 0.f;
    float b0 = 0.f, b1r = 0.f, b2r = 0.f, b3 = 0.f;
#pragma unroll 4
    for (int k = 0; k < KS; ++k) {
        const float xv = xs[k];
        const float* row = Wp + (size_t)k * NTOT;
        const float4 w0 = *reinterpret_cast<const float4*>(row);
        const float4 w1 = *reinterpret_cast<const float4*>(row + 1024);
        a0 = fmaf(xv, w0.x, a0);
        a1 = fmaf(xv, w0.y, a1);
        a2 = fmaf(xv, w0.z, a2);
        a3 = fmaf(xv, w0.w, a3);
        b0 = fmaf(xv, w1.x, b0);
        b1r = fmaf(xv, w1.y, b1r);
        b2r = fmaf(xv, w1.z, b2r);
        b3 = fmaf(xv, w1.w, b3);
    }
    float* op = Pout + (size_t)by * NTOT + ncol;
    *reinterpret_cast<float4*>(op)        = make_float4(a0, a1, a2, a3);
    *reinterpret_cast<float4*>(op + 1024) = make_float4(b0, b1r, b2r, b3);
}

// tail 1: 16 blocks; partial[b] = sum over its 256 cols of (sum_s P6[s][n])^2
template <int SPREV>
__global__ __launch_bounds__(256) void reduce_sq_partial(const float* __restrict__ P6,
                                                         float* __restrict__ partial) {
    const int n = blockIdx.x * 256 + threadIdx.x;
    float acc = 0.f;
#pragma unroll 8
    for (int s = 0; s < SPREV; ++s) acc += P6[(size_t)s * DD + n];
    float sq = acc * acc;
    for (int off = 32; off; off >>= 1) sq += __shfl_down(sq, off);
    __shared__ float ls[4];
    const int wid = threadIdx.x >> 6;
    if ((threadIdx.x & 63) == 0) ls[wid] = sq;
    __syncthreads();
    if (threadIdx.x == 0) partial[blockIdx.x] = ls[0] + ls[1] + ls[2] + ls[3];
}

// tail 2: out[DD] = sum(partial[0..15]) / DD
__global__ __launch_bounds__(64) void finalize_meansq(const float* __restrict__ partial,
                                                      float* __restrict__ dout) {
    float v = (threadIdx.x < 16) ? partial[threadIdx.x] : 0.f;
    for (int off = 8; off; off >>= 1) v += __shfl_down(v, off);
    if (threadIdx.x == 0) dout[DD] = v / (float)DD;
}

extern "C" void kernel_launch(void* const* d_in, const int* in_sizes, int n_in,
                              void* d_out, int out_size, void* d_ws, size_t ws_size,
                              hipStream_t stream) {
    const float* h  = (const float*)d_in[0];
    const float* c  = (const float*)d_in[3];
    const float* W1 = (const float*)d_in[4];   // (DD+CC) x HH row-major
    const float* b1 = (const float*)d_in[5];
    const float* W2 = (const float*)d_in[6];   // HH x DD row-major
    const float* b2 = (const float*)d_in[7];
    float* out = (float*)d_out;                // [0..4095]=dydt, [4096]=mean(drdt^2)
    float* ws = (float*)d_ws;

    // workspace (floats)
    float* P1 = ws;                 // 256 x 8192 (8 MB)
    float* P2 = P1 + 2097152;       // 512 x 4096 (8 MB)
    float* P3 = P2 + 2097152;       // 256 x 8192 (8 MB)
    float* P4 = P3 + 2097152;       // 512 x 4096 (8 MB)
    float* P5 = P4 + 2097152;       // 256 x 8192 (8 MB)
    float* P6 = P5 + 2097152;       // 512 x 4096 (8 MB)
    float* s0 = P6 + 2097152;       // 8192
    float* t0 = s0 + 8192;          // 8192
    float* a1 = t0 + 8192;          // 8192
    float* psum = a1 + 8192;        // 16

    // P1: a0 = concat(h,c) @ W1        K=8192 N=8192  grid(4,256) KS=32
    gemv_phase<S_X0, 32, 1, 1, HH, 4><<<dim3(4, 256), 256, 0, stream>>>(
        W1, nullptr, P1, h, c, b1, b2, s0, t0, a1, out);
    // P2: s0=tanh(a0+b1); F = s0 @ W2  K=8192 N=4096  grid(2,512) KS=16
    gemv_phase<S_TANH, 16, 256, HH, DD, 2><<<dim3(2, 512), 256, 0, stream>>>(
        W2, P1, P2, h, c, b1, b2, s0, t0, a1, out);
    // P3: Ff=F+b2 -> out; a1 = Ff @ W1top  K=4096 N=8192  grid(4,256) KS=16
    gemv_phase<S_BIASOUT, 16, 512, DD, HH, 4><<<dim3(4, 256), 256, 0, stream>>>(
        W1, P2, P3, h, c, b1, b2, s0, t0, a1, out);
    // P4: p1=t0*a1; v = p1 @ W2        K=8192 N=4096  grid(2,512) KS=16
    gemv_phase<S_PMUL, 16, 256, HH, DD, 2><<<dim3(2, 512), 256, 0, stream>>>(
        W2, P3, P4, h, c, b1, b2, s0, t0, a1, out);
    // P5: a2 = v @ W1top               K=4096 N=8192  grid(4,256) KS=16
    gemv_phase<S_COPY, 16, 512, DD, HH, 4><<<dim3(4, 256), 256, 0, stream>>>(
        W1, P4, P5, h, c, b1, b2, s0, t0, a1, out);
    // P6: s2=t0*(a2-s0*a1^2); C2 = s2 @ W2  K=8192 N=4096  grid(2,512) KS=16
    gemv_phase<S_S2, 16, 256, HH, DD, 2><<<dim3(2, 512), 256, 0, stream>>>(
        W2, P5, P6, h, c, b1, b2, s0, t0, a1, out);
    // tails
    reduce_sq_partial<512><<<16, 256, 0, stream>>>(P6, psum);
    finalize_meansq<<<1, 64, 0, stream>>>(psum, out);
}

// Round 8
// 212.045 us; speedup vs baseline: 8.9404x; 1.0670x over previous
//
#include <hip/hip_runtime.h>

#define DD 4096
#define HH 8192

enum Stage { S_X0 = 0, S_TANH, S_BIASOUT, S_PMUL, S_COPY, S_S2 };

typedef float vfloat4 __attribute__((ext_vector_type(4)));

// streaming inner loop: 16B/lane, optionally non-temporal (evict-first) weight loads
template <bool NT, int KS, int NTOT>
__device__ inline void stream_cols(const float* __restrict__ Wp,
                                   const float* __restrict__ xs,
                                   float* __restrict__ op) {
    float ax = 0.f, ay = 0.f, az = 0.f, aw = 0.f;
#pragma unroll 8
    for (int k = 0; k < KS; ++k) {
        const float xv = xs[k];
        const float* row = Wp + (size_t)k * NTOT;
        vfloat4 w;
        if constexpr (NT)
            w = __builtin_nontemporal_load(reinterpret_cast<const vfloat4*>(row));
        else
            w = *reinterpret_cast<const vfloat4*>(row);
        ax = fmaf(xv, w.x, ax);
        ay = fmaf(xv, w.y, ay);
        az = fmaf(xv, w.z, az);
        aw = fmaf(xv, w.w, aw);
    }
    *reinterpret_cast<float4*>(op) = make_float4(ax, ay, az, aw);
}

// ---------------- split-K GEMV phase ----------------
// prologue: build x[k0:k0+KS) in LDS (from h/c, or reduce Pprev splits + elementwise)
// stream:   Pout[by][n] = sum_{k in slice by} x[k] * W[k][n], 16B/lane
// NTMODE: 0 = cached, 1 = all rows NT, 2 = NT only for rows k0 >= DD (W1 bottom half)
template <int STAGE, int KS, int SPREV, int KPREV, int NTOT, int BX, int NTMODE>
__global__ __launch_bounds__(256) void gemv_phase(
    const float* __restrict__ W, const float* __restrict__ Pprev,
    float* __restrict__ Pout,
    const float* __restrict__ h, const float* __restrict__ c,
    const float* __restrict__ b1, const float* __restrict__ b2,
    float* __restrict__ s0g, float* __restrict__ t0g, float* __restrict__ a1g,
    float* __restrict__ outv)
{
    constexpr int GROUPS = 256 / KS;
    __shared__ float xs[KS];
    __shared__ float part[GROUPS * KS];
    const int tid = threadIdx.x;
    const int bx = blockIdx.x;
    const int by = blockIdx.y;
    const int k0 = by * KS;

    if constexpr (STAGE == S_X0) {
        if (tid < KS) {
            int k = k0 + tid;
            xs[tid] = (k < DD) ? h[k] : c[k - DD];
        }
    } else {
        const int g = tid / KS, j = tid % KS;
        float acc = 0.f;
        for (int s = g; s < SPREV; s += GROUPS)
            acc += Pprev[(size_t)s * KPREV + k0 + j];
        part[g * KS + j] = acc;
        __syncthreads();
        if (tid < KS) {
            const int k = k0 + tid;
            float tot = 0.f;
#pragma unroll
            for (int g2 = 0; g2 < GROUPS; ++g2) tot += part[g2 * KS + tid];
            float xv;
            if constexpr (STAGE == S_TANH) {
                float s = tanhf(tot + b1[k]);
                xv = s;
                if (bx == 0) { s0g[k] = s; t0g[k] = 1.f - s * s; }
            } else if constexpr (STAGE == S_BIASOUT) {
                xv = tot + b2[k];
                if (bx == 0) outv[k] = xv;
            } else if constexpr (STAGE == S_PMUL) {
                xv = t0g[k] * tot;
                if (bx == 0) a1g[k] = tot;
            } else if constexpr (STAGE == S_COPY) {
                xv = tot;
            } else { // S_S2
                float a1v = a1g[k];
                xv = t0g[k] * (tot - s0g[k] * a1v * a1v);
            }
            xs[tid] = xv;
        }
    }
    __syncthreads();

    const int ncol = bx * 1024 + tid * 4;
    const float* Wp = W + (size_t)k0 * NTOT + ncol;
    float* op = Pout + (size_t)by * NTOT + ncol;

    if constexpr (NTMODE == 0) {
        stream_cols<false, KS, NTOT>(Wp, xs, op);
    } else if constexpr (NTMODE == 1) {
        stream_cols<true, KS, NTOT>(Wp, xs, op);
    } else {
        if (k0 >= DD) stream_cols<true, KS, NTOT>(Wp, xs, op);
        else          stream_cols<false, KS, NTOT>(Wp, xs, op);
    }
}

// tail 1: 16 blocks; partial[b] = sum over its 256 cols of (sum_s P6[s][n])^2
template <int SPREV>
__global__ __launch_bounds__(256) void reduce_sq_partial(const float* __restrict__ P6,
                                                         float* __restrict__ partial) {
    const int n = blockIdx.x * 256 + threadIdx.x;
    float acc = 0.f;
#pragma unroll 8
    for (int s = 0; s < SPREV; ++s) acc += P6[(size_t)s * DD + n];
    float sq = acc * acc;
    for (int off = 32; off; off >>= 1) sq += __shfl_down(sq, off);
    __shared__ float ls[4];
    const int wid = threadIdx.x >> 6;
    if ((threadIdx.x & 63) == 0) ls[wid] = sq;
    __syncthreads();
    if (threadIdx.x == 0) partial[blockIdx.x] = ls[0] + ls[1] + ls[2] + ls[3];
}

// tail 2: out[DD] = sum(partial[0..15]) / DD
__global__ __launch_bounds__(64) void finalize_meansq(const float* __restrict__ partial,
                                                      float* __restrict__ dout) {
    float v = (threadIdx.x < 16) ? partial[threadIdx.x] : 0.f;
    for (int off = 8; off; off >>= 1) v += __shfl_down(v, off);
    if (threadIdx.x == 0) dout[DD] = v / (float)DD;
}

extern "C" void kernel_launch(void* const* d_in, const int* in_sizes, int n_in,
                              void* d_out, int out_size, void* d_ws, size_t ws_size,
                              hipStream_t stream) {
    const float* h  = (const float*)d_in[0];
    const float* c  = (const float*)d_in[3];
    const float* W1 = (const float*)d_in[4];   // (DD+CC) x HH row-major
    const float* b1 = (const float*)d_in[5];
    const float* W2 = (const float*)d_in[6];   // HH x DD row-major
    const float* b2 = (const float*)d_in[7];
    float* out = (float*)d_out;                // [0..4095]=dydt, [4096]=mean(drdt^2)
    float* ws = (float*)d_ws;

    // workspace (floats): all P matrices 1M floats (4 MB)
    float* P1 = ws;                 // 128 x 8192
    float* P2 = P1 + 1048576;       // 256 x 4096
    float* P3 = P2 + 1048576;       // 128 x 8192
    float* P4 = P3 + 1048576;       // 256 x 4096
    float* P5 = P4 + 1048576;       // 128 x 8192
    float* P6 = P5 + 1048576;       // 256 x 4096
    float* s0 = P6 + 1048576;       // 8192
    float* t0 = s0 + 8192;          // 8192
    float* a1 = t0 + 8192;          // 8192
    float* psum = a1 + 8192;        // 16

    // P1: a0 = concat(h,c) @ W1   K=8192 N=8192  grid(8,128) KS=64; NT on bottom half
    gemv_phase<S_X0, 64, 1, 1, HH, 8, 2><<<dim3(8, 128), 256, 0, stream>>>(
        W1, nullptr, P1, h, c, b1, b2, s0, t0, a1, out);
    // P2: s0=tanh(a0+b1); F = s0 @ W2   K=8192 N=4096  grid(4,256) KS=32; cached
    gemv_phase<S_TANH, 32, 128, HH, DD, 4, 0><<<dim3(4, 256), 256, 0, stream>>>(
        W2, P1, P2, h, c, b1, b2, s0, t0, a1, out);
    // P3: Ff=F+b2 -> out; a1 = Ff @ W1top   K=4096 N=8192  grid(8,128) KS=32; cached
    gemv_phase<S_BIASOUT, 32, 256, DD, HH, 8, 0><<<dim3(8, 128), 256, 0, stream>>>(
        W1, P2, P3, h, c, b1, b2, s0, t0, a1, out);
    // P4: p1=t0*a1; v = p1 @ W2   K=8192 N=4096  grid(4,256) KS=32; cached (reused P6)
    gemv_phase<S_PMUL, 32, 128, HH, DD, 4, 0><<<dim3(4, 256), 256, 0, stream>>>(
        W2, P3, P4, h, c, b1, b2, s0, t0, a1, out);
    // P5: a2 = v @ W1top   K=4096 N=8192  grid(8,128) KS=32; NT (last W1top use)
    gemv_phase<S_COPY, 32, 256, DD, HH, 8, 1><<<dim3(8, 128), 256, 0, stream>>>(
        W1, P4, P5, h, c, b1, b2, s0, t0, a1, out);
    // P6: s2=t0*(a2-s0*a1^2); C2 = s2 @ W2   K=8192 N=4096  grid(4,256) KS=32; NT
    gemv_phase<S_S2, 32, 128, HH, DD, 4, 1><<<dim3(4, 256), 256, 0, stream>>>(
        W2, P5, P6, h, c, b1, b2, s0, t0, a1, out);
    // tails
    reduce_sq_partial<256><<<16, 256, 0, stream>>>(P6, psum);
    finalize_meansq<<<1, 64, 0, stream>>>(psum, out);
}

// Round 9
// 202.779 us; speedup vs baseline: 9.3489x; 1.0457x over previous
//
#include <hip/hip_runtime.h>

#define DD 4096
#define HH 8192

enum Stage { S_X0 = 0, S_TANH, S_BIASOUT, S_PMUL, S_COPY, S_S2 };

typedef float vfloat4 __attribute__((ext_vector_type(4)));

__device__ inline unsigned short f2bf(float f) {
    unsigned int u = __float_as_uint(f);
    u += 0x7FFFu + ((u >> 16) & 1u);          // round-to-nearest-even
    return (unsigned short)(u >> 16);
}

// fp32 streaming inner loop: 16B/lane; NT = evict-first; CONV = also write bf16 copy
template <bool NT, bool CONV, int KS, int NTOT>
__device__ inline void stream_f32(const float* __restrict__ Wp,
                                  const float* __restrict__ xs,
                                  float* __restrict__ op,
                                  unsigned short* __restrict__ Wbp) {
    float ax = 0.f, ay = 0.f, az = 0.f, aw = 0.f;
#pragma unroll 8
    for (int k = 0; k < KS; ++k) {
        const float xv = xs[k];
        const float* row = Wp + (size_t)k * NTOT;
        vfloat4 w;
        if constexpr (NT)
            w = __builtin_nontemporal_load(reinterpret_cast<const vfloat4*>(row));
        else
            w = *reinterpret_cast<const vfloat4*>(row);
        ax = fmaf(xv, w.x, ax);
        ay = fmaf(xv, w.y, ay);
        az = fmaf(xv, w.z, az);
        aw = fmaf(xv, w.w, aw);
        if constexpr (CONV) {
            ushort4 o;
            o.x = f2bf(w.x); o.y = f2bf(w.y); o.z = f2bf(w.z); o.w = f2bf(w.w);
            *reinterpret_cast<ushort4*>(Wbp + (size_t)k * NTOT) = o;
        }
    }
    *reinterpret_cast<float4*>(op) = make_float4(ax, ay, az, aw);
}

// generic split-K prologue: build x[k0:k0+KS) in LDS
template <int STAGE, int KS, int SPREV, int KPREV>
__device__ inline void prologue(const float* __restrict__ Pprev,
                                const float* __restrict__ h, const float* __restrict__ c,
                                const float* __restrict__ b1, const float* __restrict__ b2,
                                float* __restrict__ s0g, float* __restrict__ t0g,
                                float* __restrict__ a1g, float* __restrict__ outv,
                                float* xs, float* part, int k0, int bx)
{
    constexpr int GROUPS = 256 / KS;
    const int tid = threadIdx.x;
    if constexpr (STAGE == S_X0) {
        if (tid < KS) {
            int k = k0 + tid;
            xs[tid] = (k < DD) ? h[k] : c[k - DD];
        }
    } else {
        const int g = tid / KS, j = tid % KS;
        float acc = 0.f;
        for (int s = g; s < SPREV; s += GROUPS)
            acc += Pprev[(size_t)s * KPREV + k0 + j];
        part[g * KS + j] = acc;
        __syncthreads();
        if (tid < KS) {
            const int k = k0 + tid;
            float tot = 0.f;
#pragma unroll
            for (int g2 = 0; g2 < GROUPS; ++g2) tot += part[g2 * KS + tid];
            float xv;
            if constexpr (STAGE == S_TANH) {
                float s = tanhf(tot + b1[k]);
                xv = s;
                if (bx == 0) { s0g[k] = s; t0g[k] = 1.f - s * s; }
            } else if constexpr (STAGE == S_BIASOUT) {
                xv = tot + b2[k];
                if (bx == 0) outv[k] = xv;
            } else if constexpr (STAGE == S_PMUL) {
                xv = t0g[k] * tot;
                if (bx == 0) a1g[k] = tot;
            } else if constexpr (STAGE == S_COPY) {
                xv = tot;
            } else { // S_S2
                float a1v = a1g[k];
                xv = t0g[k] * (tot - s0g[k] * a1v * a1v);
            }
            xs[tid] = xv;
        }
    }
    __syncthreads();
}

// fp32 GEMV phase. NTMODE: 0=cached, 1=all NT, 2=NT for k0>=DD (+conv for k0<DD if CONV)
template <int STAGE, int KS, int SPREV, int KPREV, int NTOT, int NTMODE, bool CONV>
__global__ __launch_bounds__(256) void gemv_f32(
    const float* __restrict__ W, const float* __restrict__ Pprev,
    float* __restrict__ Pout, unsigned short* __restrict__ Wb,
    const float* __restrict__ h, const float* __restrict__ c,
    const float* __restrict__ b1, const float* __restrict__ b2,
    float* __restrict__ s0g, float* __restrict__ t0g, float* __restrict__ a1g,
    float* __restrict__ outv)
{
    __shared__ float xs[KS];
    __shared__ float part[256];
    const int bx = blockIdx.x, by = blockIdx.y;
    const int k0 = by * KS;
    prologue<STAGE, KS, SPREV, KPREV>(Pprev, h, c, b1, b2, s0g, t0g, a1g, outv,
                                      xs, part, k0, bx);

    const int ncol = bx * 1024 + threadIdx.x * 4;
    const float* Wp = W + (size_t)k0 * NTOT + ncol;
    float* op = Pout + (size_t)by * NTOT + ncol;
    unsigned short* Wbp = CONV ? (Wb + (size_t)k0 * NTOT + ncol) : nullptr;

    if constexpr (NTMODE == 0) {
        stream_f32<false, false, KS, NTOT>(Wp, xs, op, nullptr);
    } else if constexpr (NTMODE == 1) {
        stream_f32<true, false, KS, NTOT>(Wp, xs, op, nullptr);
    } else {
        if (k0 >= DD) stream_f32<true, false, KS, NTOT>(Wp, xs, op, nullptr);
        else          stream_f32<false, CONV, KS, NTOT>(Wp, xs, op, Wbp);
    }
}

// bf16 GEMV phase (P3, P5): 8 cols/thread via uint4 (16B/lane), weights L3-hot
template <int STAGE, int KS, int SPREV, int KPREV, int NTOT>
__global__ __launch_bounds__(256) void gemv_b16(
    const unsigned short* __restrict__ Wb, const float* __restrict__ Pprev,
    float* __restrict__ Pout,
    const float* __restrict__ h, const float* __restrict__ c,
    const float* __restrict__ b1, const float* __restrict__ b2,
    float* __restrict__ s0g, float* __restrict__ t0g, float* __restrict__ a1g,
    float* __restrict__ outv)
{
    __shared__ float xs[KS];
    __shared__ float part[256];
    const int bx = blockIdx.x, by = blockIdx.y;
    const int k0 = by * KS;
    prologue<STAGE, KS, SPREV, KPREV>(Pprev, h, c, b1, b2, s0g, t0g, a1g, outv,
                                      xs, part, k0, bx);

    const int ncol = bx * 2048 + threadIdx.x * 8;
    const unsigned short* Wp = Wb + (size_t)k0 * NTOT + ncol;
    float a0 = 0.f, a1 = 0.f, a2 = 0.f, a3 = 0.f;
    float a4 = 0.f, a5 = 0.f, a6 = 0.f, a7 = 0.f;
#pragma unroll 8
    for (int k = 0; k < KS; ++k) {
        const float xv = xs[k];
        const uint4 w = *reinterpret_cast<const uint4*>(Wp + (size_t)k * NTOT);
        a0 = fmaf(xv, __uint_as_float(w.x << 16), a0);
        a1 = fmaf(xv, __uint_as_float(w.x & 0xFFFF0000u), a1);
        a2 = fmaf(xv, __uint_as_float(w.y << 16), a2);
        a3 = fmaf(xv, __uint_as_float(w.y & 0xFFFF0000u), a3);
        a4 = fmaf(xv, __uint_as_float(w.z << 16), a4);
        a5 = fmaf(xv, __uint_as_float(w.z & 0xFFFF0000u), a5);
        a6 = fmaf(xv, __uint_as_float(w.w << 16), a6);
        a7 = fmaf(xv, __uint_as_float(w.w & 0xFFFF0000u), a7);
    }
    float* op = Pout + (size_t)by * NTOT + ncol;
    *reinterpret_cast<float4*>(op)     = make_float4(a0, a1, a2, a3);
    *reinterpret_cast<float4*>(op + 4) = make_float4(a4, a5, a6, a7);
}

// tail 1: partial[b] = sum over 256 cols of (sum_s P6[s][n])^2
template <int SPREV>
__global__ __launch_bounds__(256) void reduce_sq_partial(const float* __restrict__ P6,
                                                         float* __restrict__ partial) {
    const int n = blockIdx.x * 256 + threadIdx.x;
    float acc = 0.f;
#pragma unroll 8
    for (int s = 0; s < SPREV; ++s) acc += P6[(size_t)s * DD + n];
    float sq = acc * acc;
    for (int off = 32; off; off >>= 1) sq += __shfl_down(sq, off);
    __shared__ float ls[4];
    const int wid = threadIdx.x >> 6;
    if ((threadIdx.x & 63) == 0) ls[wid] = sq;
    __syncthreads();
    if (threadIdx.x == 0) partial[blockIdx.x] = ls[0] + ls[1] + ls[2] + ls[3];
}

// tail 2: out[DD] = sum(partial[0..15]) / DD
__global__ __launch_bounds__(64) void finalize_meansq(const float* __restrict__ partial,
                                                      float* __restrict__ dout) {
    float v = (threadIdx.x < 16) ? partial[threadIdx.x] : 0.f;
    for (int off = 8; off; off >>= 1) v += __shfl_down(v, off);
    if (threadIdx.x == 0) dout[DD] = v / (float)DD;
}

extern "C" void kernel_launch(void* const* d_in, const int* in_sizes, int n_in,
                              void* d_out, int out_size, void* d_ws, size_t ws_size,
                              hipStream_t stream) {
    const float* h  = (const float*)d_in[0];
    const float* c  = (const float*)d_in[3];
    const float* W1 = (const float*)d_in[4];   // (DD+CC) x HH row-major
    const float* b1 = (const float*)d_in[5];
    const float* W2 = (const float*)d_in[6];   // HH x DD row-major
    const float* b2 = (const float*)d_in[7];
    float* out = (float*)d_out;                // [0..4095]=dydt, [4096]=mean(drdt^2)
    float* ws = (float*)d_ws;

    // workspace (floats)
    float* P1 = ws;                 // 128 x 8192 (4 MB)
    float* P2 = P1 + 1048576;       // 256 x 4096 (4 MB)
    float* P3 = P2 + 1048576;       // 256 x 8192 (8 MB)
    float* P4 = P3 + 2097152;       // 256 x 4096 (4 MB)
    float* P5 = P4 + 1048576;       // 256 x 8192 (8 MB)
    float* P6 = P5 + 2097152;       // 256 x 4096 (4 MB)
    float* s0 = P6 + 1048576;       // 8192
    float* t0 = s0 + 8192;          // 8192
    float* a1 = t0 + 8192;          // 8192
    float* psum = a1 + 8192;        // 16
    unsigned short* W1b = (unsigned short*)(psum + 64);  // 4096 x 8192 bf16 (64 MB)

    // P1: a0 = concat(h,c) @ W1   K=8192 N=8192 grid(8,128) KS=64
    //     top half cached + converted to W1b; bottom half NT (single use)
    gemv_f32<S_X0, 64, 1, 1, HH, 2, true><<<dim3(8, 128), 256, 0, stream>>>(
        W1, nullptr, P1, W1b, h, c, b1, b2, s0, t0, a1, out);
    // P2: s0=tanh(a0+b1); F = s0 @ W2   K=8192 N=4096 grid(4,256) KS=32, cached
    gemv_f32<S_TANH, 32, 128, HH, DD, 0, false><<<dim3(4, 256), 256, 0, stream>>>(
        W2, P1, P2, nullptr, h, c, b1, b2, s0, t0, a1, out);
    // P3: Ff=F+b2 -> out; a1 = Ff @ W1b   K=4096 N=8192 grid(4,256) KS=16 (bf16, L3)
    gemv_b16<S_BIASOUT, 16, 256, DD, HH><<<dim3(4, 256), 256, 0, stream>>>(
        W1b, P2, P3, h, c, b1, b2, s0, t0, a1, out);
    // P4: p1=t0*a1; v = p1 @ W2   K=8192 N=4096 grid(4,256) KS=32, cached (L3-hot)
    gemv_f32<S_PMUL, 32, 256, HH, DD, 0, false><<<dim3(4, 256), 256, 0, stream>>>(
        W2, P3, P4, nullptr, h, c, b1, b2, s0, t0, a1, out);
    // P5: a2 = v @ W1b   K=4096 N=8192 grid(4,256) KS=16 (bf16, L3)
    gemv_b16<S_COPY, 16, 256, DD, HH><<<dim3(4, 256), 256, 0, stream>>>(
        W1b, P4, P5, h, c, b1, b2, s0, t0, a1, out);
    // P6: s2=t0*(a2-s0*a1^2); C2 = s2 @ W2   K=8192 N=4096 grid(4,256) KS=32, NT (last use)
    gemv_f32<S_S2, 32, 256, HH, DD, 1, false><<<dim3(4, 256), 256, 0, stream>>>(
        W2, P5, P6, nullptr, h, c, b1, b2, s0, t0, a1, out);
    // tails
    reduce_sq_partial<256><<<16, 256, 0, stream>>>(P6, psum);
    finalize_meansq<<<1, 64, 0, stream>>>(psum, out);
}